// Round 1
// baseline (2523.121 us; speedup 1.0000x reference)
//
#include <hip/hip_runtime.h>
#include <cstdint>
#include <cstddef>

#define T_STEPS 1000
#define NS      512
#define HID     128
#define DOUT    20
#define XPAD    129   // x tile row pad (bank-conflict-free lane reads)
#define W2PITCH 65    // float2 row pitch for paired weight tables (129 rows: 128 + zero row)

// ---------------------------------------------------------------------------
// Pass 0: dense precompute D[row][o] = dot(x_row, Wi1[o][:]) using the exact
// 4-accumulator stride-4 fmaf chain that was verified bit-exact vs numpy in
// round 1 (a_i sums k ≡ i mod 4 ascending; final (a0+a1)+(a2+a3)). DO NOT
// change this order: spike thresholds make the dynamics chaotic to 1-ulp flips.
// Block: 512 threads (8 waves) x 128 rows. Wave w -> o in [16w, 16w+16),
// lane ln -> rows {ln, 64+ln}. grid = 4*Tc blocks (rows flat over chunk).
// ---------------------------------------------------------------------------
extern "C" __global__ void __launch_bounds__(512, 1)
srnn_dense(const float* __restrict__ x, const float* __restrict__ Wi1,
           float* __restrict__ D, int t0, int Tc)
{
    extern __shared__ float sm[];
    float* xs = sm;                    // [128 rows][XPAD]
    float* Wl = sm + 128 * XPAD;       // Wi1 row-major [128][128]
    const int tid = threadIdx.x;
    const int w = tid >> 6, ln = tid & 63;
    const int rb = blockIdx.x * 128;   // chunk-row base

    for (int i = tid; i < HID * HID / 4; i += 512)
        ((float4*)Wl)[i] = ((const float4*)Wi1)[i];
    for (int i = tid; i < 128 * 32; i += 512) {
        int r = i >> 5, kq = i & 31;
        int cr = rb + r;
        int s = cr / Tc, trel = cr - s * Tc;     // chunk row -> (sample, t)
        float4 v = ((const float4*)x)[((size_t)s * T_STEPS + t0 + trel) * 32 + kq];
        float* dst = &xs[r * XPAD + 4 * kq];
        dst[0] = v.x; dst[1] = v.y; dst[2] = v.z; dst[3] = v.w;
    }
    __syncthreads();

    const float* xr0 = xs + ln * XPAD;
    const float* xr1 = xs + (64 + ln) * XPAD;
    for (int og = 0; og < 4; ++og) {
        const int o = 16 * w + 4 * og;
        float a[2][4][4];
        #pragma unroll
        for (int r = 0; r < 2; ++r)
            #pragma unroll
            for (int j = 0; j < 4; ++j)
                #pragma unroll
                for (int i = 0; i < 4; ++i) a[r][j][i] = 0.f;

        #pragma unroll 4
        for (int k = 0; k < HID; k += 4) {
            float4 wv[4];
            #pragma unroll
            for (int j = 0; j < 4; ++j)
                wv[j] = *(const float4*)&Wl[(o + j) * HID + k];   // wave-uniform b128
            float xa0[4], xa1[4];
            #pragma unroll
            for (int i = 0; i < 4; ++i) { xa0[i] = xr0[k + i]; xa1[i] = xr1[k + i]; }
            #pragma unroll
            for (int j = 0; j < 4; ++j) {
                a[0][j][0] = fmaf(xa0[0], wv[j].x, a[0][j][0]);
                a[0][j][1] = fmaf(xa0[1], wv[j].y, a[0][j][1]);
                a[0][j][2] = fmaf(xa0[2], wv[j].z, a[0][j][2]);
                a[0][j][3] = fmaf(xa0[3], wv[j].w, a[0][j][3]);
                a[1][j][0] = fmaf(xa1[0], wv[j].x, a[1][j][0]);
                a[1][j][1] = fmaf(xa1[1], wv[j].y, a[1][j][1]);
                a[1][j][2] = fmaf(xa1[2], wv[j].z, a[1][j][2]);
                a[1][j][3] = fmaf(xa1[3], wv[j].w, a[1][j][3]);
            }
        }
        #pragma unroll
        for (int r = 0; r < 2; ++r) {
            float4 dv;
            dv.x = (a[r][0][0] + a[r][0][1]) + (a[r][0][2] + a[r][0][3]);
            dv.y = (a[r][1][0] + a[r][1][1]) + (a[r][1][2] + a[r][1][3]);
            dv.z = (a[r][2][0] + a[r][2][1]) + (a[r][2][2] + a[r][2][3]);
            dv.w = (a[r][3][0] + a[r][3][1]) + (a[r][3][2] + a[r][3][3]);
            *(float4*)&D[(size_t)(rb + 64 * r + ln) * HID + o] = dv;
        }
    }
}

// ---------------------------------------------------------------------------
// Branchless ascending 128-bit bit-walker. Returns next set-bit index
// (m0 bits 0..63 first, then m1 as 64..127) or 128 when exhausted.
// Index 128 points at a zeroed LDS row -> fold adds exact +0.0 at the END
// of the ascending chain (identity; bit-exact).
// ---------------------------------------------------------------------------
__device__ __forceinline__ int next128z(unsigned long long& lo, unsigned long long& hi)
{
    unsigned long long l = lo, h = hi;
    int jl = (int)__builtin_ctzll(l | 0x8000000000000000ULL);
    int jh = (int)__builtin_ctzll(h | 0x8000000000000000ULL);
    int j  = l ? jl : (h ? 64 + jh : 128);
    lo = l & (l - 1);
    hi = l ? h : (h & (h - 1));
    return j;
}

// Paired-weight walk: rl/rh accumulate W2[j].x/.y over set bits in ascending j.
// 8 independent ds_read_b64 issued per batch BEFORE the fold -> one LDS
// latency per batch instead of one per spike (loads return in-order; the
// compiler's counted lgkmcnt overlaps fold with outstanding reads).
__device__ __forceinline__ void walk2(const float2* __restrict__ W2,
                                      unsigned long long m0, unsigned long long m1,
                                      int ln, float& rl, float& rh)
{
    unsigned long long lo = m0, hi = m1;
    int n = __popcll(m0) + __popcll(m1);
    while (n > 0) {                       // wave-uniform trip count
        int jj[8];
        #pragma unroll
        for (int u = 0; u < 8; ++u) jj[u] = next128z(lo, hi);
        float2 v[8];
        #pragma unroll
        for (int u = 0; u < 8; ++u) v[u] = W2[jj[u] * W2PITCH + ln];
        #pragma unroll
        for (int u = 0; u < 8; ++u) { rl += v[u].x; rh += v[u].y; }
        n -= 8;
    }
}

// Stage a [o][j] row-major 128x128 weight matrix into the paired-transposed
// LDS table W2f[(j*W2PITCH + (o&63))*2 + (o>>6)] = W[o][j], plus zero row 128.
__device__ __forceinline__ void stage_w2(float* W2f, const float* __restrict__ W, int tid)
{
    for (int i = tid; i < HID * HID / 4; i += 128) {
        int o = i >> 5, jq = i & 31;
        float4 v = ((const float4*)W)[i];
        int c = o >> 6, o2 = o & 63;
        W2f[((4 * jq + 0) * W2PITCH + o2) * 2 + c] = v.x;
        W2f[((4 * jq + 1) * W2PITCH + o2) * 2 + c] = v.y;
        W2f[((4 * jq + 2) * W2PITCH + o2) * 2 + c] = v.z;
        W2f[((4 * jq + 3) * W2PITCH + o2) * 2 + c] = v.w;
    }
    for (int i = tid; i < 2 * W2PITCH; i += 128)
        W2f[128 * W2PITCH * 2 + i] = 0.f;
}

// ---------------------------------------------------------------------------
// Pass 1: layer-1 recurrence. One wave per sample; lane ln owns neurons
// {ln, 64+ln}. Spike masks live in registers via ballots -> NO barriers and
// no LDS traffic in the t-loop except the sparse Wh1 sums (ascending j,
// bit-exact, now batched 8-deep). D streamed with an 8-deep register
// prefetch pipeline.
// ---------------------------------------------------------------------------
extern "C" __global__ void __launch_bounds__(128, 1)
srnn_layer1(const float* __restrict__ D, const float* __restrict__ Wh1,
            const float* __restrict__ bi1, const float* __restrict__ bh1,
            ulonglong2* __restrict__ masks, ulonglong2* __restrict__ state,
            int t0, int Tc, int first)
{
    extern __shared__ float smw[];             // [129][W2PITCH] float2
    const float2* W2 = (const float2*)smw;
    const int tid = threadIdx.x, w = tid >> 6, ln = tid & 63;
    const int s = 2 * blockIdx.x + w;

    stage_w2(smw, Wh1, tid);

    const float bil = bi1[ln], bih = bi1[64 + ln];
    const float bhl = bh1[ln], bhh = bh1[64 + ln];
    unsigned long long m0 = 0ULL, m1 = 0ULL;
    if (!first) { ulonglong2 st = state[s]; m0 = st.x; m1 = st.y; }

    const float* Drow = D + (size_t)s * Tc * HID;
    float dl[8], dh[8];
    #pragma unroll
    for (int p = 0; p < 8; ++p) {
        int ti = p < Tc ? p : Tc - 1;
        dl[p] = Drow[ti * HID + ln];
        dh[p] = Drow[ti * HID + 64 + ln];
    }
    __syncthreads();

    for (int tt = 0; tt < Tc; tt += 8) {
        #pragma unroll
        for (int u = 0; u < 8; ++u) {
            int t = tt + u;
            if (t >= Tc) break;                       // wave-uniform
            float dense_l = dl[u], dense_h = dh[u];
            int tp = (t + 8 < Tc) ? t + 8 : Tc - 1;   // clamped prefetch
            dl[u] = Drow[tp * HID + ln];
            dh[u] = Drow[tp * HID + 64 + ln];

            float rl = 0.f, rh = 0.f;                 // ascending-j, bit-exact
            walk2(W2, m0, m1, ln, rl, rh);

            float hl = ((dense_l + bil) + rl) + bhl;  // reference add order
            float hh = ((dense_h + bih) + rh) + bhh;
            m0 = __ballot(hl >= 1.0f);
            m1 = __ballot(hh >= 1.0f);
            if (ln == 0) {
                ulonglong2 mv; mv.x = m0; mv.y = m1;
                masks[(size_t)s * T_STEPS + (t0 + t)] = mv;
            }
        }
    }
    if (ln == 0) { ulonglong2 st; st.x = m0; st.y = m1; state[s] = st; }
}

// ---------------------------------------------------------------------------
// Pass 2: layer-2 recurrence + output accumulation. Fully sparse; masks in
// registers (ballots), 8-deep s1-mask prefetch; no barriers in t-loop.
// All three walks batched 8-deep like layer 1.
// ---------------------------------------------------------------------------
extern "C" __global__ void __launch_bounds__(128, 1)
srnn_layer2(const ulonglong2* __restrict__ masks,
            const float* __restrict__ Wi2, const float* __restrict__ bi2,
            const float* __restrict__ Wh2, const float* __restrict__ bh2,
            const float* __restrict__ Wo,  const float* __restrict__ bo,
            float* __restrict__ out)
{
    extern __shared__ float sm2[];
    float* WIf = sm2;                              // Wi2 paired table (float2 view)
    float* WHf = sm2 + 129 * W2PITCH * 2;          // Wh2 paired table
    float* WOt = sm2 + 2 * 129 * W2PITCH * 2;      // Wo^T [129][20] (row 128 = 0)
    const float2* WI = (const float2*)WIf;
    const float2* WH = (const float2*)WHf;
    const int tid = threadIdx.x, w = tid >> 6, ln = tid & 63;
    const int s = 2 * blockIdx.x + w;

    stage_w2(WIf, Wi2, tid);
    stage_w2(WHf, Wh2, tid);
    for (int i = tid; i < DOUT * HID / 4; i += 128) {
        int o = i >> 5, jq = i & 31;
        float4 v = ((const float4*)Wo)[i];
        WOt[(4 * jq + 0) * DOUT + o] = v.x; WOt[(4 * jq + 1) * DOUT + o] = v.y;
        WOt[(4 * jq + 2) * DOUT + o] = v.z; WOt[(4 * jq + 3) * DOUT + o] = v.w;
    }
    for (int i = tid; i < DOUT; i += 128) WOt[128 * DOUT + i] = 0.f;

    const float bil = bi2[ln], bih = bi2[64 + ln];
    const float bhl = bh2[ln], bhh = bh2[64 + ln];
    const bool  oth = (ln < DOUT);
    const float bol = oth ? bo[ln] : 0.f;

    const ulonglong2* mrow = masks + (size_t)s * T_STEPS;
    ulonglong2 mb[8];
    #pragma unroll
    for (int p = 0; p < 8; ++p) mb[p] = mrow[p];
    unsigned long long p0 = 0ULL, p1 = 0ULL;
    float acc = 0.f;
    __syncthreads();

    for (int tt = 0; tt < T_STEPS; tt += 8) {
        #pragma unroll
        for (int u = 0; u < 8; ++u) {
            int t = tt + u;
            ulonglong2 s1 = mb[u];
            int tp = (t + 8 < T_STEPS) ? t + 8 : T_STEPS - 1;
            mb[u] = mrow[tp];

            float Al = 0.f, Ah = 0.f;                 // s1 @ Wi2^T (ascending)
            walk2(WI, s1.x, s1.y, ln, Al, Ah);

            float Bl = 0.f, Bh = 0.f;                 // s2 @ Wh2^T (ascending)
            walk2(WH, p0, p1, ln, Bl, Bh);

            float hl = ((Al + bil) + Bl) + bhl;       // reference add order
            float hh = ((Ah + bih) + Bh) + bhh;
            p0 = __ballot(hl >= 1.0f);
            p1 = __ballot(hh >= 1.0f);

            if (oth) {                                 // s2 @ Wo^T + bo
                float d = 0.f;
                unsigned long long lo = p0, hi = p1;
                int n = __popcll(p0) + __popcll(p1);
                while (n > 0) {
                    int jj[8];
                    #pragma unroll
                    for (int v8 = 0; v8 < 8; ++v8) jj[v8] = next128z(lo, hi);
                    float vv[8];
                    #pragma unroll
                    for (int v8 = 0; v8 < 8; ++v8) vv[v8] = WOt[jj[v8] * DOUT + ln];
                    #pragma unroll
                    for (int v8 = 0; v8 < 8; ++v8) d += vv[v8];
                    n -= 8;
                }
                acc += d;                              // (acc + dot) ...
                acc += bol;                            //  ... + bo
            }
        }
    }
    if (oth) out[s * DOUT + ln] = acc / (float)T_STEPS;
}

// ---------------------------------------------------------------------------
extern "C" void kernel_launch(void* const* d_in, const int* in_sizes, int n_in,
                              void* d_out, int out_size, void* d_ws, size_t ws_size,
                              hipStream_t stream) {
    const float* x   = (const float*)d_in[0];
    const float* Wi1 = (const float*)d_in[1];
    const float* bi1 = (const float*)d_in[2];
    const float* Wh1 = (const float*)d_in[3];
    const float* bh1 = (const float*)d_in[4];
    const float* Wi2 = (const float*)d_in[5];
    const float* bi2 = (const float*)d_in[6];
    const float* Wh2 = (const float*)d_in[7];
    const float* bh2 = (const float*)d_in[8];
    const float* Wo  = (const float*)d_in[9];
    const float* bo  = (const float*)d_in[10];
    float* out = (float*)d_out;

    // ws layout: [masks 8.192 MB][layer1 state 8 KB][D chunk buffer]
    const size_t mask_bytes  = (size_t)NS * T_STEPS * sizeof(ulonglong2);
    const size_t state_bytes = (size_t)NS * sizeof(ulonglong2);
    ulonglong2* masks = (ulonglong2*)d_ws;
    ulonglong2* state = (ulonglong2*)((char*)d_ws + mask_bytes);
    float* D = (float*)((char*)d_ws + mask_bytes + state_bytes);

    size_t avail = ws_size > mask_bytes + state_bytes
                 ? ws_size - mask_bytes - state_bytes : 0;
    const size_t bytes_per_t = (size_t)NS * HID * sizeof(float);  // 256 KB
    long tcmax = (long)(avail / bytes_per_t);
    static const int divs[] = {1000, 500, 250, 200, 125, 100, 50, 40, 25, 20, 10, 8, 5, 4, 2, 1};
    int Tc = 1;
    for (int i = 0; i < 16; ++i) if (divs[i] <= tcmax) { Tc = divs[i]; break; }

    const int lds0 = (128 * XPAD + HID * HID) * (int)sizeof(float);
    const int lds1 = (129 * W2PITCH * 2) * (int)sizeof(float);
    const int lds2 = (2 * 129 * W2PITCH * 2 + 129 * DOUT) * (int)sizeof(float);
    hipFuncSetAttribute((const void*)srnn_dense,
                        hipFuncAttributeMaxDynamicSharedMemorySize, lds0);
    hipFuncSetAttribute((const void*)srnn_layer1,
                        hipFuncAttributeMaxDynamicSharedMemorySize, lds1);
    hipFuncSetAttribute((const void*)srnn_layer2,
                        hipFuncAttributeMaxDynamicSharedMemorySize, lds2);

    for (int t0 = 0; t0 < T_STEPS; t0 += Tc) {
        srnn_dense<<<4 * Tc, 512, lds0, stream>>>(x, Wi1, D, t0, Tc);
        srnn_layer1<<<NS / 2, 128, lds1, stream>>>(D, Wh1, bi1, bh1, masks, state,
                                                   t0, Tc, t0 == 0 ? 1 : 0);
    }
    srnn_layer2<<<NS / 2, 128, lds2, stream>>>(masks, Wi2, bi2, Wh2, bh2, Wo, bo, out);
}